// Round 4
// baseline (72.112 us; speedup 1.0000x reference)
//
#include <hip/hip_runtime.h>

namespace {
constexpr int kH       = 16;
constexpr int kS       = 2048;
constexpr int kD       = 64;
constexpr int kNpos    = 64;
constexpr int kHid     = 1024;  // H*D
constexpr int kChunk   = 256;   // 64 lanes * 4 floats
constexpr int kNChunks = kS / kChunk;    // 8
constexpr int kRowsPerBlock = 16;        // 4 waves * 4 rows
constexpr int kFillChunks = kNChunks - 1;  // chunks 0..6 constant-filled
}

__device__ __forceinline__ float dot4f(float4 a, float qx, float qy, float qz, float qw) {
    return fmaf(a.x, qx, fmaf(a.y, qy, fmaf(a.z, qz, a.w * qw)));
}

template <int CTRL, int ROWM>
__device__ __forceinline__ float dpp_add(float v) {
    int t = __builtin_amdgcn_update_dpp(0, __float_as_int(v), CTRL, ROWM, 0xf, true);
    return v + __int_as_float(t);
}

// 64-lane inclusive prefix sum, pure VALU (classic GCN DPP scan).
__device__ __forceinline__ float wave_incl_scan(float v) {
    v = dpp_add<0x111, 0xf>(v);  // row_shr:1
    v = dpp_add<0x112, 0xf>(v);  // row_shr:2
    v = dpp_add<0x114, 0xf>(v);  // row_shr:4
    v = dpp_add<0x118, 0xf>(v);  // row_shr:8
    v = dpp_add<0x142, 0xa>(v);  // row_bcast15 -> rows 1,3
    v = dpp_add<0x143, 0xc>(v);  // row_bcast31 -> rows 2,3
    return v;
}

__device__ __forceinline__ float bcast_lane(float v, int l) {
    return __int_as_float(__builtin_amdgcn_readlane(__float_as_int(v), l));
}

__device__ __forceinline__ float wave_sum(float v) {
    return bcast_lane(wave_incl_scan(v), 63);
}

// ---------------- Kernel 1: constant fill of chunks 0..6 ----------------
// Per row: fill = dot(q_row, pe[h][63]); then 7 KB of pure coalesced stores.
// Memcpy-class: no LDS, minimal VGPRs, max occupancy.
__global__ __launch_bounds__(256) void cope_fill_kernel(
    const float* __restrict__ query,
    const float* __restrict__ pos_emb,
    float* __restrict__ out)
{
    const int t    = threadIdx.x;
    const int lane = t & 63;
    const int wid  = t >> 6;
    const int row_base = blockIdx.x * kRowsPerBlock;
    const int h        = row_base >> 11;
    const int wrow = __builtin_amdgcn_readfirstlane(row_base + wid * 4);

    // pe[h][63][lane] — 256 B per head, L2/L3-hot.
    const float pe63 = pos_emb[(size_t)(kNpos - 1) * kHid + h * kD + lane];

    const float* qrow = query + (size_t)wrow * kD;
    const float f0 = wave_sum(qrow[0 * kD + lane] * pe63);
    const float f1 = wave_sum(qrow[1 * kD + lane] * pe63);
    const float f2 = wave_sum(qrow[2 * kD + lane] * pe63);
    const float f3 = wave_sum(qrow[3 * kD + lane] * pe63);

    float* orow = out + (size_t)wrow * kS;
    const float4 v0 = make_float4(f0, f0, f0, f0);
    const float4 v1 = make_float4(f1, f1, f1, f1);
    const float4 v2 = make_float4(f2, f2, f2, f2);
    const float4 v3 = make_float4(f3, f3, f3, f3);
    #pragma unroll
    for (int j = 0; j < kFillChunks; ++j) {
        const int off = j * kChunk + lane * 4;
        *reinterpret_cast<float4*>(orow + 0 * kS + off) = v0;
        *reinterpret_cast<float4*>(orow + 1 * kS + off) = v1;
        *reinterpret_cast<float4*>(orow + 2 * kS + off) = v2;
        *reinterpret_cast<float4*>(orow + 3 * kS + off) = v3;
    }
}

// ---------------- Kernel 2: compute the un-clamped tail ----------------
// Reverse-cumsum + interpolate + store, starting at the rightmost chunk.
// No fill loop: kernel 1 already wrote chunks 0..6; we overwrite leftward
// only while running < 63 (astronomically rare for this data, but correct).
__device__ __forceinline__ void process_row_tail(const float* __restrict__ arow,
                                                 float* __restrict__ orow,
                                                 float acc, float4 x0, int lane) {
    float running = 0.0f;
    float4 x = x0;
    for (int c = kNChunks - 1; c >= 0; --c) {
        if (c != kNChunks - 1)
            x = *reinterpret_cast<const float4*>(arow + c * kChunk + lane * 4);
        float g0 = 1.0f / (1.0f + __expf(-x.x));
        float g1 = 1.0f / (1.0f + __expf(-x.y));
        float g2 = 1.0f / (1.0f + __expf(-x.z));
        float g3 = 1.0f / (1.0f + __expf(-x.w));

        float e3 = g3;
        float e2 = e3 + g2;
        float e1 = e2 + g1;
        float e0 = e1 + g0;          // lane total

        float incl  = wave_incl_scan(e0);
        float total = bcast_lane(incl, 63);
        float sfx   = running + (total - incl);  // exclusive suffix, this lane

        float p[4] = {sfx + e0, sfx + e1, sfx + e2, sfx + e3};
        float r[4];
        #pragma unroll
        for (int i = 0; i < 4; ++i) {
            float pc = fminf(p[i], 63.0f);
            float fl = floorf(pc);
            float w  = pc - fl;
            int  fi  = (int)fl;
            int  ni  = (fi < kNpos - 1) ? fi + 1 : kNpos - 1;
            float lf = __shfl(acc, fi);
            float ln = __shfl(acc, ni);
            r[i] = fmaf(w, ln - lf, lf);
        }
        *reinterpret_cast<float4*>(orow + c * kChunk + lane * 4) =
            make_float4(r[0], r[1], r[2], r[3]);

        running += total;
        if (running >= 63.0f) break;   // clamped region beyond: already filled
    }
}

__global__ __launch_bounds__(256) void cope_tail_kernel(
    const float* __restrict__ query,
    const float* __restrict__ attn,
    const float* __restrict__ pos_emb,
    float* __restrict__ out)
{
    const int t    = threadIdx.x;
    const int lane = t & 63;
    const int wid  = t >> 6;
    const int row_base = blockIdx.x * kRowsPerBlock;
    const int h        = row_base >> 11;
    const int wrow = __builtin_amdgcn_readfirstlane(row_base + wid * 4);

    __shared__ float4 pe_lds[kNpos * 16];   // 16 KB, swizzled [n][j]

    const float* arow = attn + (size_t)wrow * kS;
    float*       orow = out  + (size_t)wrow * kS;

    // Prefetch rightmost attn chunk for all 4 rows (hides under stage+dot).
    const int tail = (kNChunks - 1) * kChunk + lane * 4;
    float4 x0 = *reinterpret_cast<const float4*>(arow + 0 * kS + tail);
    float4 x1 = *reinterpret_cast<const float4*>(arow + 1 * kS + tail);
    float4 x2 = *reinterpret_cast<const float4*>(arow + 2 * kS + tail);
    float4 x3 = *reinterpret_cast<const float4*>(arow + 3 * kS + tail);

    // Stage pe[h], swizzled: slot(n,j) = n*16 + (j ^ (n&15)).
    #pragma unroll
    for (int k = 0; k < 4; ++k) {
        const int e = t + 256 * k;
        const int n = e >> 4;
        const int j = e & 15;
        float4 p = *reinterpret_cast<const float4*>(
            pos_emb + (size_t)n * kHid + h * kD + 4 * j);
        pe_lds[(n << 4) | (j ^ (n & 15))] = p;
    }
    __syncthreads();

    // 4-row dot; lane n = position n.
    const float* qbase = query + (size_t)wrow * kD;
    float acc0 = 0.f, acc1 = 0.f, acc2 = 0.f, acc3 = 0.f;
    #pragma unroll 4
    for (int j = 0; j < 16; ++j) {
        float4 pe4 = pe_lds[(lane << 4) | (j ^ (lane & 15))];
        const float* q0 = qbase + 0 * kD + 4 * j;
        const float* q1 = qbase + 1 * kD + 4 * j;
        const float* q2 = qbase + 2 * kD + 4 * j;
        const float* q3 = qbase + 3 * kD + 4 * j;
        acc0 += dot4f(pe4, q0[0], q0[1], q0[2], q0[3]);
        acc1 += dot4f(pe4, q1[0], q1[1], q1[2], q1[3]);
        acc2 += dot4f(pe4, q2[0], q2[1], q2[2], q2[3]);
        acc3 += dot4f(pe4, q3[0], q3[1], q3[2], q3[3]);
    }

    process_row_tail(arow + 0 * kS, orow + 0 * kS, acc0, x0, lane);
    process_row_tail(arow + 1 * kS, orow + 1 * kS, acc1, x1, lane);
    process_row_tail(arow + 2 * kS, orow + 2 * kS, acc2, x2, lane);
    process_row_tail(arow + 3 * kS, orow + 3 * kS, acc3, x3, lane);
}

extern "C" void kernel_launch(void* const* d_in, const int* in_sizes, int n_in,
                              void* d_out, int out_size, void* d_ws, size_t ws_size,
                              hipStream_t stream) {
    const float* query   = (const float*)d_in[0];
    const float* attn    = (const float*)d_in[1];
    const float* pos_emb = (const float*)d_in[2];
    float* out = (float*)d_out;

    const int rows = kH * kS;                    // 32768
    dim3 grid(rows / kRowsPerBlock), block(256); // 2048 blocks x 4 waves

    // Fill first; tail kernel overwrites leftward if the cumsum hasn't
    // clamped (same stream -> ordered).
    cope_fill_kernel<<<grid, block, 0, stream>>>(query, pos_emb, out);
    cope_tail_kernel<<<grid, block, 0, stream>>>(query, attn, pos_emb, out);
}

// Round 6
// 58.033 us; speedup vs baseline: 1.2426x; 1.2426x over previous
//
#include <hip/hip_runtime.h>

namespace {
constexpr int kH       = 16;
constexpr int kS       = 2048;
constexpr int kD       = 64;
constexpr int kNpos    = 64;
constexpr int kHid     = 1024;  // H*D
constexpr int kChunk   = 256;   // 64 lanes * 4 floats
constexpr int kNChunks = kS / kChunk;    // 8
constexpr int kRowsPerBlock = 16;        // 4 waves * 4 rows
}

typedef float vfloat4 __attribute__((ext_vector_type(4)));  // native vector for nt builtins

__device__ __forceinline__ float dot4f(float4 a, float qx, float qy, float qz, float qw) {
    return fmaf(a.x, qx, fmaf(a.y, qy, fmaf(a.z, qz, a.w * qw)));
}

template <int CTRL, int ROWM>
__device__ __forceinline__ float dpp_add(float v) {
    int t = __builtin_amdgcn_update_dpp(0, __float_as_int(v), CTRL, ROWM, 0xf, true);
    return v + __int_as_float(t);
}

// 64-lane inclusive prefix sum, pure VALU (classic GCN DPP scan).
__device__ __forceinline__ float wave_incl_scan(float v) {
    v = dpp_add<0x111, 0xf>(v);  // row_shr:1
    v = dpp_add<0x112, 0xf>(v);  // row_shr:2
    v = dpp_add<0x114, 0xf>(v);  // row_shr:4
    v = dpp_add<0x118, 0xf>(v);  // row_shr:8
    v = dpp_add<0x142, 0xa>(v);  // row_bcast15 -> rows 1,3
    v = dpp_add<0x143, 0xc>(v);  // row_bcast31 -> rows 2,3
    return v;
}

__device__ __forceinline__ float bcast_lane(float v, int l) {
    return __int_as_float(__builtin_amdgcn_readlane(__float_as_int(v), l));
}

__device__ __forceinline__ void nt_store4(float* p, float a, float b, float c, float d) {
    vfloat4 v = {a, b, c, d};
    __builtin_nontemporal_store(v, reinterpret_cast<vfloat4*>(p));
}

__device__ __forceinline__ vfloat4 nt_load4(const float* p) {
    return __builtin_nontemporal_load(reinterpret_cast<const vfloat4*>(p));
}

// Reverse-cumsum + interpolate + store for one output row, then constant-fill
// the clamped prefix. All output stores are nontemporal (write-once stream);
// attn loads are nontemporal (read-once stream).
__device__ __forceinline__ void process_row(const float* __restrict__ arow,
                                            float* __restrict__ orow,
                                            float acc, vfloat4 x0, int lane) {
    const float fill = bcast_lane(acc, kNpos - 1);  // logits_int[63]
    float running = 0.0f;
    int c = kNChunks - 1;
    vfloat4 x = x0;
    for (; c >= 0; --c) {
        if (c != kNChunks - 1)
            x = nt_load4(arow + c * kChunk + lane * 4);
        float g0 = 1.0f / (1.0f + __expf(-x.x));
        float g1 = 1.0f / (1.0f + __expf(-x.y));
        float g2 = 1.0f / (1.0f + __expf(-x.z));
        float g3 = 1.0f / (1.0f + __expf(-x.w));

        // in-lane reverse inclusive sums (element i covers g[i..3])
        float e3 = g3;
        float e2 = e3 + g2;
        float e1 = e2 + g1;
        float e0 = e1 + g0;          // lane total

        float incl  = wave_incl_scan(e0);        // prefix over lane totals
        float total = bcast_lane(incl, 63);
        float sfx   = running + (total - incl);  // exclusive suffix, this lane

        float p[4] = {sfx + e0, sfx + e1, sfx + e2, sfx + e3};
        float r[4];
        #pragma unroll
        for (int i = 0; i < 4; ++i) {
            float pc = fminf(p[i], 63.0f);
            float fl = floorf(pc);
            float w  = pc - fl;
            int  fi  = (int)fl;
            int  ni  = (fi < kNpos - 1) ? fi + 1 : kNpos - 1;
            float lf = __shfl(acc, fi);
            float ln = __shfl(acc, ni);
            r[i] = fmaf(w, ln - lf, lf);   // == lf when w==0 (ceil==floor case)
        }
        nt_store4(orow + c * kChunk + lane * 4, r[0], r[1], r[2], r[3]);

        running += total;
        if (running >= 63.0f) break;   // everything left of chunk c clamps
    }
    const int fillEnd = (c > 0) ? c * kChunk : 0;
    for (int j = lane * 4; j < fillEnd; j += 256) {
        nt_store4(orow + j, fill, fill, fill, fill);
    }
}

// Block = 16 consecutive rows (same head). Wave = 4 rows.
// Phase 0: stage pe[h] (16 KB) into LDS, XOR-swizzled float4 layout.
// Phase 1: lane n computes logits_int[n] for 4 rows (ds_read_b128 amortized).
// Phase 2: per row: reverse cumsum of sigmoid(attn) (DPP scan), interpolate
//          via __shfl gather, early-exit + nt constant fill once sum >= 63.
__global__ __launch_bounds__(256) void cope_kernel(
    const float* __restrict__ query,
    const float* __restrict__ attn,
    const float* __restrict__ pos_emb,
    float* __restrict__ out)
{
    const int t    = threadIdx.x;
    const int lane = t & 63;
    const int wid  = t >> 6;
    const int row_base = blockIdx.x * kRowsPerBlock;
    const int h        = row_base >> 11;           // row / S
    const int wrow = __builtin_amdgcn_readfirstlane(row_base + wid * 4);

    __shared__ float4 pe_lds[kNpos * 16];          // 16 KB, swizzled [n][j]

    const float* arow = attn + (size_t)wrow * kS;
    float*       orow = out  + (size_t)wrow * kS;

    // Prefetch rightmost attn chunk for all 4 rows (hides under stage+dot).
    const int tail = (kNChunks - 1) * kChunk + lane * 4;
    vfloat4 x0 = nt_load4(arow + 0 * kS + tail);
    vfloat4 x1 = nt_load4(arow + 1 * kS + tail);
    vfloat4 x2 = nt_load4(arow + 2 * kS + tail);
    vfloat4 x3 = nt_load4(arow + 3 * kS + tail);

    // ---- Phase 0: stage pe[h], swizzled: slot(n,j) = n*16 + (j ^ (n&15)) ----
    #pragma unroll
    for (int k = 0; k < 4; ++k) {
        const int e = t + 256 * k;       // float4 index in [0,1024)
        const int n = e >> 4;
        const int j = e & 15;
        float4 p = *reinterpret_cast<const float4*>(
            pos_emb + (size_t)n * kHid + h * kD + 4 * j);
        pe_lds[(n << 4) | (j ^ (n & 15))] = p;
    }
    __syncthreads();

    // ---- Phase 1: 4-row dot; lane n = position n ----
    const float* qbase = query + (size_t)wrow * kD;  // uniform -> s_load
    float acc0 = 0.f, acc1 = 0.f, acc2 = 0.f, acc3 = 0.f;
    #pragma unroll 4
    for (int j = 0; j < 16; ++j) {
        float4 pe4 = pe_lds[(lane << 4) | (j ^ (lane & 15))];
        const float* q0 = qbase + 0 * kD + 4 * j;
        const float* q1 = qbase + 1 * kD + 4 * j;
        const float* q2 = qbase + 2 * kD + 4 * j;
        const float* q3 = qbase + 3 * kD + 4 * j;
        acc0 += dot4f(pe4, q0[0], q0[1], q0[2], q0[3]);
        acc1 += dot4f(pe4, q1[0], q1[1], q1[2], q1[3]);
        acc2 += dot4f(pe4, q2[0], q2[1], q2[2], q2[3]);
        acc3 += dot4f(pe4, q3[0], q3[1], q3[2], q3[3]);
    }

    // ---- Phase 2: 4 rows, unrolled (no runtime-indexed reg arrays) ----
    process_row(arow + 0 * kS, orow + 0 * kS, acc0, x0, lane);
    process_row(arow + 1 * kS, orow + 1 * kS, acc1, x1, lane);
    process_row(arow + 2 * kS, orow + 2 * kS, acc2, x2, lane);
    process_row(arow + 3 * kS, orow + 3 * kS, acc3, x3, lane);
}

extern "C" void kernel_launch(void* const* d_in, const int* in_sizes, int n_in,
                              void* d_out, int out_size, void* d_ws, size_t ws_size,
                              hipStream_t stream) {
    const float* query   = (const float*)d_in[0];
    const float* attn    = (const float*)d_in[1];
    const float* pos_emb = (const float*)d_in[2];
    float* out = (float*)d_out;

    const int rows = kH * kS;                    // 32768
    dim3 grid(rows / kRowsPerBlock), block(256); // 2048 blocks x 4 waves
    cope_kernel<<<grid, block, 0, stream>>>(query, attn, pos_emb, out);
}